// Round 1
// baseline (348.877 us; speedup 1.0000x reference)
//
#include <hip/hip_runtime.h>

// XY model log-density: out[b] = BETA * sum_s [cos(th[up(s)]-th[s]) + cos(th[right(s)]-th[s])]
// Lattice 64x64 periodic; up(s)=(s+64)&4095, right(s)=(s&~63)|((s+1)&63)  (matches _make_shift).
// Memory-bound: 256 MiB input read once per dispatch -> ~43 us floor at 6.3 TB/s.

#define LAT_L     64
#define NSITE     4096          // 64*64
#define BLOCK     256
#define PER_THR   (NSITE / BLOCK)   // 16 sites per thread
#define NSAMPLE   16384

__global__ __launch_bounds__(BLOCK)
void xy_logdensity_kernel(const float* __restrict__ state, float* __restrict__ out) {
    __shared__ float th[NSITE];
    __shared__ float red[BLOCK / 64];

    const int b = blockIdx.x;
    const int t = threadIdx.x;
    const float* __restrict__ row = state + (size_t)b * NSITE;

    // --- Stage row into LDS with coalesced float4 loads: 1024 float4, 256 threads x 4 ---
    const float4* __restrict__ row4 = (const float4*)row;
    float4* th4 = (float4*)th;
#pragma unroll
    for (int k = 0; k < NSITE / 4 / BLOCK; ++k) {
        th4[t + BLOCK * k] = row4[t + BLOCK * k];
    }
    __syncthreads();

    // --- Compute: sites strided by BLOCK so consecutive lanes hit consecutive LDS banks ---
    const float inv2pi = 0.15915494309189535f; // 1/(2*pi); v_cos_f32 takes revolutions
    float sum = 0.0f;
#pragma unroll
    for (int k = 0; k < PER_THR; ++k) {
        const int s = t + BLOCK * k;
        const float ts = th[s];
        const int up    = (s + LAT_L) & (NSITE - 1);
        const int right = (s & ~(LAT_L - 1)) | ((s + 1) & (LAT_L - 1));
        sum += __cosf(th[up] - ts);
        sum += __cosf(th[right] - ts);
        (void)inv2pi;
    }

    // --- Wave-64 shuffle reduction, then cross-wave via LDS ---
#pragma unroll
    for (int off = 32; off > 0; off >>= 1)
        sum += __shfl_down(sum, off, 64);
    const int wave = t >> 6;
    if ((t & 63) == 0) red[wave] = sum;
    __syncthreads();
    if (t == 0) {
        // BETA = 1.0
        out[b] = red[0] + red[1] + red[2] + red[3];
    }
}

extern "C" void kernel_launch(void* const* d_in, const int* in_sizes, int n_in,
                              void* d_out, int out_size, void* d_ws, size_t ws_size,
                              hipStream_t stream) {
    const float* state = (const float*)d_in[0];
    // d_in[1] is the int64 shift table; its contents are the deterministic
    // 64x64 periodic roll, which we compute in-register instead of gathering.
    float* out = (float*)d_out;

    xy_logdensity_kernel<<<NSAMPLE, BLOCK, 0, stream>>>(state, out);
}